// Round 1
// 6184.008 us; speedup vs baseline: 1.0718x; 1.0718x over previous
//
#include <hip/hip_runtime.h>

#define DEV __device__ __forceinline__

constexpr int B_ = 32768;
constexpr float SCALE_ = 0.125f;   // 1/sqrt(64)
constexpr float EPS_   = 1e-5f;

// broadcast lane l's value to all lanes via v_readlane (SGPR result, VALU pipe,
// replaces ds_read_b32 broadcasts). l may be a uniform runtime value.
DEV float rl(float x, int l){
    return __int_as_float(__builtin_amdgcn_readlane(__float_as_int(x), l));
}

DEV float wsum(float x){
    #pragma unroll
    for (int m=1; m<64; m<<=1) x += __shfl_xor(x, m, 64);
    return x;
}

struct P {
    const float *query,*latent,*W1,*b1,*Wq,*bq,*Wk,*bk,*Wv,*bv,*Wo,*bo,
                *fW1,*fb1,*fW2,*fb2,*g1,*be1,*g2,*be2,
                *cWq,*cbq,*cWk,*cbk,*cWv,*cbv,*cWo,*cbo,*Wc,*bc,*Ws,*bs;
    float *o_color,*o_sigma,*o_out,*o_attn;
};

constexpr int WROW = 68;            // padded row stride (floats): 272B, 16B-aligned, b128-conflict-free
constexpr int WLDS = 2*8*WROW;      // 1088 floats per wave (Q tile + K tile only)

__global__ __launch_bounds__(256,4) void rt_fused(P p){
    __shared__ __align__(16) float sh[4*WLDS];   // 17408 B/block, wave-private regions, NO barriers
    const int wave = threadIdx.x >> 6;
    const int lane = threadIdx.x & 63;
    const int b    = (blockIdx.x<<2) + wave;
    float* lq = sh + wave*WLDS;
    float* lk = lq + 8*WROW;

    // ---------------- embed: o = relu(latent @ W1 + b1), lane = out feature ----------------
    float o[8];
    {
        const float* latb = p.latent + ((size_t)b<<12) + lane;
        float lat[8];
        #pragma unroll
        for (int s=0;s<8;++s) lat[s] = latb[s*512];          // chunk 0 (HBM stream, prefetched)
        float acc[8];
        float bb = p.b1[lane];
        #pragma unroll
        for (int s=0;s<8;++s) acc[s] = bb;
        #pragma unroll 1
        for (int cb=0; cb<8; ++cb){
            float nlat[8];
            if (cb < 7){                                     // prefetch next chunk under compute
                #pragma unroll
                for (int s=0;s<8;++s) nlat[s] = latb[s*512 + (cb+1)*64];
            }
            const float* w1 = p.W1 + cb*64*64 + lane;
            #pragma unroll 2
            for (int c=0;c<64;++c){
                float w = w1[c*64];
                #pragma unroll
                for (int s=0;s<8;++s) acc[s] = fmaf(rl(lat[s],c), w, acc[s]);
            }
            #pragma unroll
            for (int s=0;s<8;++s) lat[s] = nlat[s];
        }
        #pragma unroll
        for (int s=0;s<8;++s) o[s] = fmaxf(acc[s], 0.f);
    }

    // ---------------- transformer layers ----------------
    #pragma unroll 1
    for (int i=0;i<4;++i){
        const float* Wq_i = p.Wq + (size_t)i*16384;
        const float* Wk_i = p.Wk + (size_t)i*16384;
        const float* Wv_i = p.Wv + (size_t)i*16384;
        const float* Wo_i = p.Wo + (size_t)i*16384;
        const float* bq_i = p.bq + i*256;
        const float* bk_i = p.bk + i*256;
        const float* bv_i = p.bv + i*256;

        float accO[8];                                  // Wo output accumulator (lane = out feature)
        {
            float bb = p.bo[i*64+lane];
            #pragma unroll
            for (int s=0;s<8;++s) accO[s]=bb;
        }

        #pragma unroll 1
        for (int hg=0; hg<2; ++hg){                     // 2 heads per group: batch o-broadcasts
            float q[2][8], k[2][8], v[2][8];
            #pragma unroll
            for (int u=0;u<2;++u){
                int h = hg*2+u;
                float bqv=bq_i[h*64+lane], bkv=bk_i[h*64+lane], bvv=bv_i[h*64+lane];
                #pragma unroll
                for (int s=0;s<8;++s){ q[u][s]=bqv; k[u][s]=bkv; v[u][s]=bvv; }
            }
            const float* wqp = Wq_i + hg*128 + lane;
            const float* wkp = Wk_i + hg*128 + lane;
            const float* wvp = Wv_i + hg*128 + lane;
            #pragma unroll 2
            for (int c=0;c<64;++c){
                float a[8];
                #pragma unroll
                for (int s=0;s<8;++s) a[s]=rl(o[s],c);  // 8 broadcasts shared by 6 weight streams
                #pragma unroll
                for (int u=0;u<2;++u){
                    int off = c*256 + u*64;
                    float wq=wqp[off], wk=wkp[off], wv=wvp[off];
                    #pragma unroll
                    for (int s=0;s<8;++s){
                        q[u][s]=fmaf(a[s],wq,q[u][s]);
                        k[u][s]=fmaf(a[s],wk,k[u][s]);
                        v[u][s]=fmaf(a[s],wv,v[u][s]);
                    }
                }
            }
            #pragma unroll
            for (int u=0;u<2;++u){                      // per head: scores -> softmax -> PV -> partial Wo
                const int h=hg*2+u;
                #pragma unroll
                for (int s=0;s<8;++s){                  // stage the one true transpose
                    lq[s*WROW+lane]=q[u][s];
                    lk[s*WROW+lane]=k[u][s];
                }
                const int qq=lane>>3, kk=lane&7;
                float s0=0.f,s1=0.f,s2=0.f,s3=0.f;
                #pragma unroll
                for (int dd=0; dd<16; ++dd){            // ds_read_b128, stride-68 rows: conflict-free
                    float4 qa=*(const float4*)(lq + qq*WROW + dd*4);
                    float4 kb=*(const float4*)(lk + kk*WROW + dd*4);
                    s0=fmaf(qa.x,kb.x,s0);
                    s1=fmaf(qa.y,kb.y,s1);
                    s2=fmaf(qa.z,kb.z,s2);
                    s3=fmaf(qa.w,kb.w,s3);
                }
                float sc=((s0+s1)+(s2+s3))*SCALE_;
                float mx=sc;
                mx=fmaxf(mx,__shfl_xor(mx,1,64));
                mx=fmaxf(mx,__shfl_xor(mx,2,64));
                mx=fmaxf(mx,__shfl_xor(mx,4,64));
                float e=__expf(sc-mx);
                float sm=e;
                sm+=__shfl_xor(sm,1,64);
                sm+=__shfl_xor(sm,2,64);
                sm+=__shfl_xor(sm,4,64);
                float pr=e/sm;
                p.o_attn[((size_t)b<<10) + i*256 + h*64 + lane]=pr;
                float O[8];
                #pragma unroll
                for (int s=0;s<8;++s) O[s]=0.f;
                #pragma unroll
                for (int q2=0;q2<8;++q2){
                    #pragma unroll
                    for (int k2=0;k2<8;++k2)
                        O[q2]=fmaf(rl(pr,q2*8+k2), v[u][k2], O[q2]);
                }
                const float* wop = Wo_i + h*64*64 + lane;
                #pragma unroll 4
                for (int dd=0;dd<64;++dd){
                    float w=wop[dd*64];
                    #pragma unroll
                    for (int s=0;s<8;++s) accO[s]=fmaf(rl(O[s],dd), w, accO[s]);
                }
            }
        }
        // residual + LN1
        {
            float g=p.g1[i*64+lane], be=p.be1[i*64+lane];
            #pragma unroll
            for (int s=0;s<8;++s){
                float x=accO[s]+o[s];
                float m=wsum(x)*0.015625f;
                float xm=x-m;
                float var=wsum(xm*xm)*0.015625f;
                o[s]=fmaf(xm*rsqrtf(var+EPS_), g, be);
            }
        }
        // FF: relu(o@fW1+fb1)@fW2+fb2, residual + LN2
        {
            float f1[8];
            float bb=p.fb1[i*64+lane];
            #pragma unroll
            for (int s=0;s<8;++s) f1[s]=bb;
            const float* w1p = p.fW1 + i*4096 + lane;
            #pragma unroll 2
            for (int c=0;c<64;++c){
                float w=w1p[c*64];
                #pragma unroll
                for (int s=0;s<8;++s) f1[s]=fmaf(rl(o[s],c), w, f1[s]);
            }
            #pragma unroll
            for (int s=0;s<8;++s) f1[s]=fmaxf(f1[s],0.f);
            float f2[8];
            float bb2=p.fb2[i*64+lane];
            #pragma unroll
            for (int s=0;s<8;++s) f2[s]=bb2;
            const float* w2p = p.fW2 + i*4096 + lane;
            #pragma unroll 2
            for (int c=0;c<64;++c){
                float w=w2p[c*64];
                #pragma unroll
                for (int s=0;s<8;++s) f2[s]=fmaf(rl(f1[s],c), w, f2[s]);
            }
            float g=p.g2[i*64+lane], be=p.be2[i*64+lane];
            #pragma unroll
            for (int s=0;s<8;++s){
                float x=f2[s]+o[s];
                float m=wsum(x)*0.015625f;
                float xm=x-m;
                float var=wsum(xm*xm)*0.015625f;
                o[s]=fmaf(xm*rsqrtf(var+EPS_), g, be);
            }
        }
    }

    // ---------------- out ----------------
    {
        float* op = p.o_out + ((size_t)b<<9) + lane;
        #pragma unroll
        for (int s=0;s<8;++s) op[s*64]=o[s];
    }
    // ---------------- sigma ----------------
    {
        float mx=o[0];
        #pragma unroll
        for (int s=1;s<8;++s) mx=fmaxf(mx,o[s]);
        float sg=wsum(mx*p.Ws[lane]);
        if (lane==0) p.o_sigma[b]=sg+p.bs[0];
    }
    // ---------------- cross attention + color ----------------
    {
        float qr = p.query[((size_t)b<<6)+lane];
        float accC = p.cbo[lane];
        #pragma unroll 1
        for (int h=0;h<4;++h){
            // Qc (single query row), 4 partial accumulators to break the chain
            float q0=p.cbq[h*64+lane], q1=0.f,q2=0.f,q3=0.f;
            const float* wq = p.cWq + h*64 + lane;
            #pragma unroll 4
            for (int c=0;c<64;c+=4){
                q0=fmaf(rl(qr,c+0), wq[(c+0)*256], q0);
                q1=fmaf(rl(qr,c+1), wq[(c+1)*256], q1);
                q2=fmaf(rl(qr,c+2), wq[(c+2)*256], q2);
                q3=fmaf(rl(qr,c+3), wq[(c+3)*256], q3);
            }
            float Qc=(q0+q1)+(q2+q3);
            // K,V projections of out
            float Kc[8], Vc[8];
            float bkv=p.cbk[h*64+lane], bvv=p.cbv[h*64+lane];
            #pragma unroll
            for (int s=0;s<8;++s){ Kc[s]=bkv; Vc[s]=bvv; }
            const float* wk = p.cWk + h*64 + lane;
            const float* wv = p.cWv + h*64 + lane;
            #pragma unroll 2
            for (int c=0;c<64;++c){
                float a[8];
                #pragma unroll
                for (int s=0;s<8;++s) a[s]=rl(o[s],c);
                float wkv=wk[c*256], wvv=wv[c*256];
                #pragma unroll
                for (int s=0;s<8;++s){
                    Kc[s]=fmaf(a[s],wkv,Kc[s]);
                    Vc[s]=fmaf(a[s],wvv,Vc[s]);
                }
            }
            // scores via full-wave reduce (uniform results), softmax over s=8
            float scs[8];
            #pragma unroll
            for (int s=0;s<8;++s) scs[s]=wsum(Qc*Kc[s])*SCALE_;
            float m=scs[0];
            #pragma unroll
            for (int s=1;s<8;++s) m=fmaxf(m,scs[s]);
            float e[8], sm=0.f;
            #pragma unroll
            for (int s=0;s<8;++s){ e[s]=__expf(scs[s]-m); sm+=e[s]; }
            float inv=1.f/sm;
            float Oc=0.f;
            #pragma unroll
            for (int s=0;s<8;++s) Oc=fmaf(e[s]*inv, Vc[s], Oc);
            // partial cWo (4-way split chain)
            const float* wo = p.cWo + h*64*64 + lane;
            float a0=0.f,a1=0.f,a2=0.f,a3=0.f;
            #pragma unroll 4
            for (int dd=0;dd<64;dd+=4){
                a0=fmaf(rl(Oc,dd+0), wo[(dd+0)*64], a0);
                a1=fmaf(rl(Oc,dd+1), wo[(dd+1)*64], a1);
                a2=fmaf(rl(Oc,dd+2), wo[(dd+2)*64], a2);
                a3=fmaf(rl(Oc,dd+3), wo[(dd+3)*64], a3);
            }
            accC += (a0+a1)+(a2+a3);
        }
        float r=fmaxf(accC,0.f);
        float c0=wsum(r*p.Wc[lane*3+0]);
        float c1=wsum(r*p.Wc[lane*3+1]);
        float c2=wsum(r*p.Wc[lane*3+2]);
        if (lane==0){
            float* oc = p.o_color + (size_t)b*3;
            oc[0]=c0+p.bc[0];
            oc[1]=c1+p.bc[1];
            oc[2]=c2+p.bc[2];
        }
    }
}

extern "C" void kernel_launch(void* const* d_in, const int* in_sizes, int n_in,
                              void* d_out, int out_size, void* d_ws, size_t ws_size,
                              hipStream_t stream){
    const float* const* ins = (const float* const*)d_in;
    P p;
    p.query=ins[0];  p.latent=ins[1]; p.W1=ins[2];   p.b1=ins[3];
    p.Wq=ins[4];     p.bq=ins[5];     p.Wk=ins[6];   p.bk=ins[7];
    p.Wv=ins[8];     p.bv=ins[9];     p.Wo=ins[10];  p.bo=ins[11];
    p.fW1=ins[12];   p.fb1=ins[13];   p.fW2=ins[14]; p.fb2=ins[15];
    p.g1=ins[16];    p.be1=ins[17];   p.g2=ins[18];  p.be2=ins[19];
    p.cWq=ins[20];   p.cbq=ins[21];   p.cWk=ins[22]; p.cbk=ins[23];
    p.cWv=ins[24];   p.cbv=ins[25];   p.cWo=ins[26]; p.cbo=ins[27];
    p.Wc=ins[28];    p.bc=ins[29];    p.Ws=ins[30];  p.bs=ins[31];
    float* out=(float*)d_out;
    p.o_color = out;
    p.o_sigma = out + (size_t)B_*3;
    p.o_out   = out + (size_t)B_*4;
    p.o_attn  = out + (size_t)B_*4 + (size_t)B_*512;
    hipLaunchKernelGGL(rt_fused, dim3(B_/4), dim3(256), 0, stream, p);
}